// Round 10
// baseline (1441.482 us; speedup 1.0000x reference)
//
#include <hip/hip_runtime.h>
#include <math.h>

#define H_ENC 128
#define H_DEC 256
#define L_SRC 512
#define T_DEC 96
#define B_TOT 1024

typedef _Float16 half8 __attribute__((ext_vector_type(8)));
typedef float f32x4 __attribute__((ext_vector_type(4)));

#define MFMA16(A, B, C) __builtin_amdgcn_mfma_f32_16x16x32_f16((A), (B), (C), 0, 0, 0)

__device__ __forceinline__ unsigned packu(float a, float b) {
    union { _Float16 h[2]; unsigned u; } x; x.h[0] = (_Float16)a; x.h[1] = (_Float16)b; return x.u;
}

// division/clamp-free (NaN-safe at +-inf)
__device__ __forceinline__ float sigmoidf_(float x) {
    return __builtin_amdgcn_rcpf(1.f + __expf(-x));
}
__device__ __forceinline__ float tanhf_(float x) {
    return 1.f - 2.f * __builtin_amdgcn_rcpf(__expf(2.f * x) + 1.f);
}

// ---------------- flag init (fresh every launch: graph-replay safe) ----------------
#define CNT_STRIDE 104
__global__ void zero_cnt(int* cnt) {
    int i = blockIdx.x * blockDim.x + threadIdx.x;
    if (i < 64 * CNT_STRIDE) cnt[i] = 0;
}

// ---------------- Encoder v7: EB=4 gbuf-redistributed + bias-fold + setprio ----------------
#define EB 4
#define HPAD 136
__global__ __launch_bounds__(512, 4)
void encoder_eb4r(
    const float* __restrict__ source,
    const float* __restrict__ Wih_f, const float* __restrict__ Whh_f, const float* __restrict__ b_f,
    const float* __restrict__ Wih_b, const float* __restrict__ Whh_b, const float* __restrict__ b_b,
    float* __restrict__ h0, float* __restrict__ c0)
{
    const int dir = blockIdx.x & 1;
    const int bg  = blockIdx.x >> 1;       // 0..255
    const int t   = threadIdx.x;
    const int w   = t >> 6;                // wave 0..7
    const int l   = t & 63;
    const int col = l & 15;
    const int grp = l >> 4;

    const float* Wih = dir ? Wih_b : Wih_f;
    const float* Whh = dir ? Whh_b : Whh_f;
    const float* bb  = dir ? b_b   : b_f;

    __shared__ float    xsT[L_SRC][EB];        // 8 KB [step][batch]
    __shared__ _Float16 hbuf[2][EB][HPAD];     // 2.2 KB double-buffered
    __shared__ float    gbuf[4][EB][H_ENC];    // 8 KB raw gates [gate][batch][elem]

    {
        const float* srcb = source + (size_t)bg * EB * L_SRC;
        for (int i = t; i < EB * L_SRC; i += 512) {
            int b = i >> 9, st = i & 511;
            xsT[st][b] = srcb[i];              // coalesced read
        }
        for (int i = t; i < 2 * EB * HPAD; i += 512)
            ((_Float16*)hbuf)[i] = (_Float16)0.f;
    }

    // B-frags for my 4 tiles; bias per tile folded into acc init.
    half8 wf[4][4];
    float bias4[4];
    #pragma unroll
    for (int tau = 0; tau < 4; ++tau) {
        const int n = 4 * w + tau;
        const int grow = (n >> 3) * H_ENC + 16 * (n & 7) + col;
        bias4[tau] = bb[grow];
        const float* wr = Whh + (size_t)grow * H_ENC;
        #pragma unroll
        for (int kt = 0; kt < 4; ++kt) {
            const float* p = wr + 32 * kt + 8 * grp;
            float4 v0 = *reinterpret_cast<const float4*>(p);
            float4 v1 = *reinterpret_cast<const float4*>(p + 4);
            half8 h;
            h[0] = (_Float16)v0.x; h[1] = (_Float16)v0.y; h[2] = (_Float16)v0.z; h[3] = (_Float16)v0.w;
            h[4] = (_Float16)v1.x; h[5] = (_Float16)v1.y; h[6] = (_Float16)v1.z; h[7] = (_Float16)v1.w;
            wf[tau][kt] = h;
        }
    }

    // phase-3 identity: one (batch, elem) per lane
    const int ub = t >> 7;                 // batch 0..3
    const int ue = t & 127;                // h-elem 0..127
    const float wI = Wih[ue];
    const float wF = Wih[H_ENC + ue];
    const float wG = Wih[2*H_ENC + ue];
    const float wO = Wih[3*H_ENC + ue];

    float c = 0.f, hlast = 0.f;
    __syncthreads();

    int cur = 0;
    for (int s = 0; s < L_SRC; ++s) {
        const int step = dir ? (L_SRC - 1 - s) : s;

        // ---- phase 1: MFMA; A-cols 0..3 = batches, rest zero ----
        half8 a0 = {0,0,0,0,0,0,0,0}, a1 = a0, a2 = a0, a3 = a0;
        if (col < EB) {
            a0 = *reinterpret_cast<const half8*>(&hbuf[cur][col][ 0 + 8 * grp]);
            a1 = *reinterpret_cast<const half8*>(&hbuf[cur][col][32 + 8 * grp]);
            a2 = *reinterpret_cast<const half8*>(&hbuf[cur][col][64 + 8 * grp]);
            a3 = *reinterpret_cast<const half8*>(&hbuf[cur][col][96 + 8 * grp]);
        }

        f32x4 acc0 = {bias4[0], bias4[0], bias4[0], bias4[0]};
        f32x4 acc1 = {bias4[1], bias4[1], bias4[1], bias4[1]};
        f32x4 acc2 = {bias4[2], bias4[2], bias4[2], bias4[2]};
        f32x4 acc3 = {bias4[3], bias4[3], bias4[3], bias4[3]};
        __builtin_amdgcn_s_setprio(1);
        acc0 = MFMA16(a0, wf[0][0], acc0); acc0 = MFMA16(a1, wf[0][1], acc0);
        acc0 = MFMA16(a2, wf[0][2], acc0); acc0 = MFMA16(a3, wf[0][3], acc0);
        acc1 = MFMA16(a0, wf[1][0], acc1); acc1 = MFMA16(a1, wf[1][1], acc1);
        acc1 = MFMA16(a2, wf[1][2], acc1); acc1 = MFMA16(a3, wf[1][3], acc1);
        acc2 = MFMA16(a0, wf[2][0], acc2); acc2 = MFMA16(a1, wf[2][1], acc2);
        acc2 = MFMA16(a2, wf[2][2], acc2); acc2 = MFMA16(a3, wf[2][3], acc2);
        acc3 = MFMA16(a0, wf[3][0], acc3); acc3 = MFMA16(a1, wf[3][1], acc3);
        acc3 = MFMA16(a2, wf[3][2], acc3); acc3 = MFMA16(a3, wf[3][3], acc3);
        __builtin_amdgcn_s_setprio(0);

        // ---- phase 2: valid C rows (batch = r, grp==0) -> gbuf ----
        if (grp == 0) {
            #pragma unroll
            for (int tau = 0; tau < 4; ++tau) {
                const int n = 4 * w + tau;
                const int G = n >> 3;
                const int e = 16 * (n & 7) + col;
                const f32x4 acc = (tau == 0) ? acc0 : (tau == 1) ? acc1 : (tau == 2) ? acc2 : acc3;
                #pragma unroll
                for (int r = 0; r < 4; ++r)
                    gbuf[G][r][e] = acc[r];
            }
        }
        __syncthreads();

        // ---- phase 3: one LSTM update per lane (bias already in gbuf) ----
        {
            float x = xsT[step][ub];
            float gi = sigmoidf_(gbuf[0][ub][ue] + wI * x);
            float gf = sigmoidf_(gbuf[1][ub][ue] + wF * x);
            float gg = tanhf_  (gbuf[2][ub][ue] + wG * x);
            float go = sigmoidf_(gbuf[3][ub][ue] + wO * x);
            c = gf * c + gi * gg;
            float h = go * tanhf_(c);
            hlast = h;
            hbuf[cur ^ 1][ub][ue] = (_Float16)h;
        }
        __syncthreads();
        cur ^= 1;
    }

    h0[(size_t)(bg * EB + ub) * (2 * H_ENC) + dir * H_ENC + ue] = hlast;
    c0[(size_t)(bg * EB + ub) * (2 * H_ENC) + dir * H_ENC + ue] = c;
}

// ---------------- Decoder v3: 4-chain interleave, 64 blocks ----------------
// Block (G2 = blk&15, q = blk>>4) serves groups {4*G2..4*G2+3} chunk q.
// Weights shared across chains. While one chain's flags/stores propagate
// through LLC, the block issues the other 3 -> latency hidden.
#define DB 16
#define NCH 4
__global__ __launch_bounds__(512, 2)
void decoder_mc(
    const float* __restrict__ Wih,   // [1024]
    const float* __restrict__ bb,    // [1024]
    const float* __restrict__ outW,  // [256]
    const float* __restrict__ outb,  // [1]
    const float* __restrict__ h0,    // [B,256]
    const float* __restrict__ c0,    // [B,256]
    const float* __restrict__ Whh,   // [1024,256]
    unsigned* __restrict__ hx,       // [2][1024][128] u32 (f16 pairs)
    int* __restrict__ cnt,           // [64][CNT_STRIDE]
    float* __restrict__ out)         // [B,T]
{
    const int blk = blockIdx.x;      // 0..63
    const int G2  = blk & 15;        // supergroup (4 batch-groups)
    const int q   = blk >> 4;        // chunk 0..3 (siblings at stride 16)
    const int t   = threadIdx.x;
    const int w   = t >> 6;
    const int l   = t & 63;
    const int col = l & 15;
    const int grp = l >> 4;
    const int u   = w >> 1;
    const int fo  = w & 1;

    __shared__ unsigned hlU[NCH][DB][132];     // 33 KB: all 4 chains' h^(s-1)
    __shared__ float    exch[4][2][DB][16];    // reused per chain (barrier-bracketed)
    __shared__ unsigned hnewU[DB][32];         // reused per chain
    __shared__ float    yl[NCH][DB];
    __shared__ float    owl[H_DEC];
    int* mycnt = cnt + (size_t)(G2 * NCH) * CNT_STRIDE;   // 4 consecutive groups

    if (t < H_DEC) owl[t] = outW[t];

    const int j0 = 64 * q + 16 * u + col;
    const int rA = (fo ? 256 : 0) + j0;
    const int rB = (fo ? 768 : 512) + j0;

    half8 wfA[8], wfB[8];
    #pragma unroll
    for (int kt = 0; kt < 8; ++kt) {
        const float* pa = Whh + (size_t)rA * H_DEC + 32 * kt + 8 * grp;
        const float* pb = Whh + (size_t)rB * H_DEC + 32 * kt + 8 * grp;
        float4 a0 = *reinterpret_cast<const float4*>(pa);
        float4 a1 = *reinterpret_cast<const float4*>(pa + 4);
        float4 b0 = *reinterpret_cast<const float4*>(pb);
        float4 b1 = *reinterpret_cast<const float4*>(pb + 4);
        half8 ha, hb;
        ha[0]=(_Float16)a0.x; ha[1]=(_Float16)a0.y; ha[2]=(_Float16)a0.z; ha[3]=(_Float16)a0.w;
        ha[4]=(_Float16)a1.x; ha[5]=(_Float16)a1.y; ha[6]=(_Float16)a1.z; ha[7]=(_Float16)a1.w;
        hb[0]=(_Float16)b0.x; hb[1]=(_Float16)b0.y; hb[2]=(_Float16)b0.z; hb[3]=(_Float16)b0.w;
        hb[4]=(_Float16)b1.x; hb[5]=(_Float16)b1.y; hb[6]=(_Float16)b1.z; hb[7]=(_Float16)b1.w;
        wfA[kt] = ha; wfB[kt] = hb;
    }

    const float bI = bb[j0],       wI = Wih[j0];
    const float bF = bb[256 + j0], wF = Wih[256 + j0];
    const float bG = bb[512 + j0], wG = Wih[512 + j0];
    const float bO = bb[768 + j0], wO = Wih[768 + j0];
    const float ob = outb[0];

    // c state per chain (static indices only)
    float c[NCH][4];
    #pragma unroll
    for (int ch = 0; ch < NCH; ++ch) {
        const int bg = G2 * NCH + ch;
        #pragma unroll
        for (int r = 0; r < 4; ++r)
            c[ch][r] = c0[(size_t)(bg * DB + 4 * grp + r) * H_DEC + j0];
    }

    // prologue: publish chunk q of h^(0) for all 4 chains
    #pragma unroll
    for (int ch = 0; ch < NCH; ++ch) {
        const int bg = G2 * NCH + ch;
        int batch = t >> 5, pair = t & 31;
        int e = 64 * q + 2 * pair;
        const float* hp = h0 + (size_t)(bg * DB + batch) * H_DEC + e;
        unsigned v = packu(hp[0], hp[1]);
        __hip_atomic_store(&hx[(size_t)(bg * DB + batch) * 128 + 32 * q + pair], v,
                           __ATOMIC_RELAXED, __HIP_MEMORY_SCOPE_AGENT);
    }
    __syncthreads();   // drains vmcnt: stores ack'd before flags
    if (t < NCH)
        __hip_atomic_fetch_add(&mycnt[(size_t)t * CNT_STRIDE + 0], 1,
                               __ATOMIC_RELAXED, __HIP_MEMORY_SCOPE_AGENT);

    for (int s = 1; s <= T_DEC; ++s) {
        const int rb = (s - 1) & 1, wb = s & 1;

        // wait all 4 chains' step s-1 published (4 lanes poll in parallel)
        if (t < NCH) {
            while (__hip_atomic_load(&mycnt[(size_t)t * CNT_STRIDE + (s - 1)],
                                     __ATOMIC_RELAXED, __HIP_MEMORY_SCOPE_AGENT) < 4)
                __builtin_amdgcn_s_sleep(1);
        }
        __syncthreads();

        // load all 4 chains' h^(s-1): flat idx = G2-relative batch*128 + within
        #pragma unroll
        for (int i = 0; i < 16; ++i) {
            int idx = t + 512 * i;               // 0..8191
            ((unsigned*)hlU)[(idx >> 7) * 132 + (idx & 127)] =
                __hip_atomic_load(&hx[(size_t)rb * (B_TOT * 128) + (size_t)G2 * 8192 + idx],
                                  __ATOMIC_RELAXED, __HIP_MEMORY_SCOPE_AGENT);
        }
        __syncthreads();

        #pragma unroll
        for (int ch = 0; ch < NCH; ++ch) {
            const int bg = G2 * NCH + ch;
            const char* hbase = reinterpret_cast<const char*>(hlU[ch]);

            // y^(s-1) for this chain (+ out[s-2])
            {
                int batch = t >> 5, seg = t & 31;
                half8 hv = *reinterpret_cast<const half8*>(hbase + batch * 528 + seg * 16);
                float sum = 0.f;
                #pragma unroll
                for (int j = 0; j < 8; ++j) sum += (float)hv[j] * owl[8 * seg + j];
                #pragma unroll
                for (int m = 1; m < 32; m <<= 1) sum += __shfl_xor(sum, m);
                if (seg == 0) {
                    float yv = sum + ob;
                    yl[ch][batch] = (s == 1) ? 0.f : yv;
                    if (q == 0 && s >= 2) out[(size_t)(bg * DB + batch) * T_DEC + (s - 2)] = yv;
                }
            }

            half8 a[8];
            #pragma unroll
            for (int kt = 0; kt < 8; ++kt)
                a[kt] = *reinterpret_cast<const half8*>(hbase + col * 528 + (32 * kt + 8 * grp) * 2);

            f32x4 accA = {0.f, 0.f, 0.f, 0.f};
            f32x4 accB = {0.f, 0.f, 0.f, 0.f};
            __builtin_amdgcn_s_setprio(1);
            #pragma unroll
            for (int kt = 0; kt < 8; ++kt) {
                accA = MFMA16(a[kt], wfA[kt], accA);
                accB = MFMA16(a[kt], wfB[kt], accB);
            }
            __builtin_amdgcn_s_setprio(0);

            if (fo) {
                #pragma unroll
                for (int r = 0; r < 4; ++r) {
                    exch[u][0][4 * grp + r][col] = accA[r] + bF;
                    exch[u][1][4 * grp + r][col] = accB[r] + bO;
                }
            }
            __syncthreads();   // exch + yl visible; hlU[ch] reads done

            if (!fo) {
                #pragma unroll
                for (int r = 0; r < 4; ++r) {
                    float yb = yl[ch][4 * grp + r];
                    float gi = sigmoidf_(accA[r] + bI + wI * yb);
                    float gg = tanhf_  (accB[r] + bG + wG * yb);
                    float gf = sigmoidf_(exch[u][0][4 * grp + r][col] + wF * yb);
                    float go = sigmoidf_(exch[u][1][4 * grp + r][col] + wO * yb);
                    c[ch][r] = gf * c[ch][r] + gi * gg;
                    float h = go * tanhf_(c[ch][r]);
                    reinterpret_cast<_Float16*>(hnewU)[(4 * grp + r) * 64 + 16 * u + col] = (_Float16)h;
                }
            }
            __syncthreads();   // hnewU complete

            {
                int batch = t >> 5, pair = t & 31;
                __hip_atomic_store(
                    &hx[(size_t)wb * (B_TOT * 128) + (size_t)(bg * DB + batch) * 128 + 32 * q + pair],
                    hnewU[batch][pair], __ATOMIC_RELAXED, __HIP_MEMORY_SCOPE_AGENT);
            }
            // next chain's hnewU writes are ordered behind its own exch barrier
        }

        __syncthreads();   // drains vmcnt: all 4 chains' stores ack'd
        if (t < NCH)
            __hip_atomic_fetch_add(&mycnt[(size_t)t * CNT_STRIDE + s], 1,
                                   __ATOMIC_RELAXED, __HIP_MEMORY_SCOPE_AGENT);
    }

    // epilogue: y^(96) -> out[95] (h^(96) sits in buffer wb(96)=0)
    if (t < NCH) {
        while (__hip_atomic_load(&mycnt[(size_t)t * CNT_STRIDE + T_DEC],
                                 __ATOMIC_RELAXED, __HIP_MEMORY_SCOPE_AGENT) < 4)
            __builtin_amdgcn_s_sleep(1);
    }
    __syncthreads();
    #pragma unroll
    for (int i = 0; i < 16; ++i) {
        int idx = t + 512 * i;
        ((unsigned*)hlU)[(idx >> 7) * 132 + (idx & 127)] =
            __hip_atomic_load(&hx[(size_t)G2 * 8192 + idx],
                              __ATOMIC_RELAXED, __HIP_MEMORY_SCOPE_AGENT);
    }
    __syncthreads();
    if (q == 0) {
        #pragma unroll
        for (int ch = 0; ch < NCH; ++ch) {
            const int bg = G2 * NCH + ch;
            int batch = t >> 5, seg = t & 31;
            half8 hv = *reinterpret_cast<const half8*>(
                reinterpret_cast<const char*>(hlU[ch]) + batch * 528 + seg * 16);
            float sum = 0.f;
            #pragma unroll
            for (int j = 0; j < 8; ++j) sum += (float)hv[j] * owl[8 * seg + j];
            #pragma unroll
            for (int m = 1; m < 32; m <<= 1) sum += __shfl_xor(sum, m);
            if (seg == 0)
                out[(size_t)(bg * DB + batch) * T_DEC + (T_DEC - 1)] = sum + ob;
        }
    }
}

extern "C" void kernel_launch(void* const* d_in, const int* in_sizes, int n_in,
                              void* d_out, int out_size, void* d_ws, size_t ws_size,
                              hipStream_t stream) {
    const float* source = (const float*)d_in[0];
    const float* eWih_f = (const float*)d_in[2];
    const float* eWhh_f = (const float*)d_in[3];
    const float* eb_f   = (const float*)d_in[4];
    const float* eWih_b = (const float*)d_in[5];
    const float* eWhh_b = (const float*)d_in[6];
    const float* eb_b   = (const float*)d_in[7];
    const float* dWih   = (const float*)d_in[8];
    const float* dWhh   = (const float*)d_in[9];
    const float* db     = (const float*)d_in[10];
    const float* oW     = (const float*)d_in[11];
    const float* obp    = (const float*)d_in[12];
    float* out = (float*)d_out;

    float*    h0  = (float*)d_ws;                             // 1 MB
    float*    c0  = h0 + (size_t)B_TOT * H_DEC;               // 1 MB
    unsigned* hx  = (unsigned*)(c0 + (size_t)B_TOT * H_DEC);  // 1 MB
    int*      cnt = (int*)(hx + (size_t)2 * B_TOT * 128);     // 64*104 ints

    zero_cnt<<<(64 * CNT_STRIDE + 255) / 256, 256, 0, stream>>>(cnt);
    encoder_eb4r<<<256 * 2, 512, 0, stream>>>(
        source, eWih_f, eWhh_f, eb_f, eWih_b, eWhh_b, eb_b, h0, c0);
    decoder_mc<<<64, 512, 0, stream>>>(
        dWih, db, oW, obp, h0, c0, dWhh, hx, cnt, out);
}

// Round 12
// 771.173 us; speedup vs baseline: 1.8692x; 1.8692x over previous
//
#include <hip/hip_runtime.h>
#include <math.h>

#define H_ENC 128
#define H_DEC 256
#define L_SRC 512
#define T_DEC 96
#define B_TOT 1024

typedef _Float16 half8 __attribute__((ext_vector_type(8)));
typedef float f32x4 __attribute__((ext_vector_type(4)));

#define MFMA16(A, B, C) __builtin_amdgcn_mfma_f32_16x16x32_f16((A), (B), (C), 0, 0, 0)

__device__ __forceinline__ unsigned packu(float a, float b) {
    union { _Float16 h[2]; unsigned u; } x; x.h[0] = (_Float16)a; x.h[1] = (_Float16)b; return x.u;
}

// division/clamp-free (NaN-safe at +-inf)
__device__ __forceinline__ float sigmoidf_(float x) {
    return __builtin_amdgcn_rcpf(1.f + __expf(-x));
}
__device__ __forceinline__ float tanhf_(float x) {
    return 1.f - 2.f * __builtin_amdgcn_rcpf(__expf(2.f * x) + 1.f);
}

// ---------------- flag init (fresh every launch: graph-replay safe) ----------------
#define CNT_STRIDE 104
__global__ void zero_cnt(int* cnt) {
    int i = blockIdx.x * blockDim.x + threadIdx.x;
    if (i < 64 * CNT_STRIDE) cnt[i] = 0;
}

// ---------------- Encoder v8: EB=8, 1024 thr, gbuf + guarded A + bias-fold ----------------
// grid = 128*2 = 256 blocks (1/CU, 16 waves). Wave w owns N-tiles {2w,2w+1}
// (wf[2][4] = 32 VGPRs + bias folded into acc init). A-reads guarded col<8
// over an 8-row hbuf (kills R7's 5e7 bank conflicts). Phase 3: lane t = one
// (batch,elem) update, all 1024 lanes useful (1024 = 8 batches x 128 elems).
#define EB 8
#define HPAD 136
__global__ __launch_bounds__(1024)
void encoder_eb8(
    const float* __restrict__ source,
    const float* __restrict__ Wih_f, const float* __restrict__ Whh_f, const float* __restrict__ b_f,
    const float* __restrict__ Wih_b, const float* __restrict__ Whh_b, const float* __restrict__ b_b,
    float* __restrict__ h0, float* __restrict__ c0)
{
    const int dir = blockIdx.x & 1;
    const int bg  = blockIdx.x >> 1;       // 0..127
    const int t   = threadIdx.x;           // 0..1023
    const int w   = t >> 6;                // wave 0..15
    const int l   = t & 63;
    const int col = l & 15;
    const int grp = l >> 4;

    const float* Wih = dir ? Wih_b : Wih_f;
    const float* Whh = dir ? Whh_b : Whh_f;
    const float* bb  = dir ? b_b   : b_f;

    __shared__ float    xsT[L_SRC][EB];        // 16 KB [step][batch]
    __shared__ _Float16 hbuf[2][EB][HPAD];     // 4.3 KB double-buffered
    __shared__ float    gbuf[4][EB][H_ENC];    // 16 KB raw gates [gate][batch][elem]

    {
        const float* srcb = source + (size_t)bg * EB * L_SRC;
        for (int i = t; i < EB * L_SRC; i += 1024) {
            int b = i >> 9, st = i & 511;
            xsT[st][b] = srcb[i];              // coalesced global read
        }
        for (int i = t; i < 2 * EB * HPAD; i += 1024)
            ((_Float16*)hbuf)[i] = (_Float16)0.f;
    }

    // B-frags for my 2 tiles (n = 2w+tau); bias folded into acc init.
    half8 wf[2][4];
    float bias2[2];
    #pragma unroll
    for (int tau = 0; tau < 2; ++tau) {
        const int n = 2 * w + tau;
        const int grow = (n >> 3) * H_ENC + 16 * (n & 7) + col;
        bias2[tau] = bb[grow];
        const float* wr = Whh + (size_t)grow * H_ENC;
        #pragma unroll
        for (int kt = 0; kt < 4; ++kt) {
            const float* p = wr + 32 * kt + 8 * grp;
            float4 v0 = *reinterpret_cast<const float4*>(p);
            float4 v1 = *reinterpret_cast<const float4*>(p + 4);
            half8 h;
            h[0] = (_Float16)v0.x; h[1] = (_Float16)v0.y; h[2] = (_Float16)v0.z; h[3] = (_Float16)v0.w;
            h[4] = (_Float16)v1.x; h[5] = (_Float16)v1.y; h[6] = (_Float16)v1.z; h[7] = (_Float16)v1.w;
            wf[tau][kt] = h;
        }
    }

    // phase-3 identity: one (batch, elem) per lane
    const int ub = t >> 7;                 // batch 0..7
    const int ue = t & 127;                // h-elem 0..127
    const float wI = Wih[ue];
    const float wF = Wih[H_ENC + ue];
    const float wG = Wih[2*H_ENC + ue];
    const float wO = Wih[3*H_ENC + ue];

    float c = 0.f, hlast = 0.f;
    __syncthreads();

    int cur = 0;
    for (int s = 0; s < L_SRC; ++s) {
        const int step = dir ? (L_SRC - 1 - s) : s;

        // ---- phase 1: MFMA; A-cols 0..7 = batches, rest zero ----
        half8 a0 = {0,0,0,0,0,0,0,0}, a1 = a0, a2 = a0, a3 = a0;
        if (col < EB) {
            a0 = *reinterpret_cast<const half8*>(&hbuf[cur][col][ 0 + 8 * grp]);
            a1 = *reinterpret_cast<const half8*>(&hbuf[cur][col][32 + 8 * grp]);
            a2 = *reinterpret_cast<const half8*>(&hbuf[cur][col][64 + 8 * grp]);
            a3 = *reinterpret_cast<const half8*>(&hbuf[cur][col][96 + 8 * grp]);
        }

        f32x4 acc0 = {bias2[0], bias2[0], bias2[0], bias2[0]};
        f32x4 acc1 = {bias2[1], bias2[1], bias2[1], bias2[1]};
        __builtin_amdgcn_s_setprio(1);
        acc0 = MFMA16(a0, wf[0][0], acc0); acc0 = MFMA16(a1, wf[0][1], acc0);
        acc0 = MFMA16(a2, wf[0][2], acc0); acc0 = MFMA16(a3, wf[0][3], acc0);
        acc1 = MFMA16(a0, wf[1][0], acc1); acc1 = MFMA16(a1, wf[1][1], acc1);
        acc1 = MFMA16(a2, wf[1][2], acc1); acc1 = MFMA16(a3, wf[1][3], acc1);
        __builtin_amdgcn_s_setprio(0);

        // ---- phase 2: valid C rows (batch = 4*grp+r < 8 -> grp<2) -> gbuf ----
        if (grp < 2) {
            #pragma unroll
            for (int tau = 0; tau < 2; ++tau) {
                const int n = 2 * w + tau;
                const int G = n >> 3;
                const int e = 16 * (n & 7) + col;
                const f32x4 acc = tau ? acc1 : acc0;
                #pragma unroll
                for (int r = 0; r < 4; ++r)
                    gbuf[G][4 * grp + r][e] = acc[r];
            }
        }
        __syncthreads();

        // ---- phase 3: one LSTM update per lane (bias already in gbuf) ----
        {
            float x = xsT[step][ub];
            float gi = sigmoidf_(gbuf[0][ub][ue] + wI * x);
            float gf = sigmoidf_(gbuf[1][ub][ue] + wF * x);
            float gg = tanhf_  (gbuf[2][ub][ue] + wG * x);
            float go = sigmoidf_(gbuf[3][ub][ue] + wO * x);
            c = gf * c + gi * gg;
            float h = go * tanhf_(c);
            hlast = h;
            hbuf[cur ^ 1][ub][ue] = (_Float16)h;
        }
        __syncthreads();
        cur ^= 1;
    }

    h0[(size_t)(bg * EB + ub) * (2 * H_ENC) + dir * H_ENC + ue] = hlast;
    c0[(size_t)(bg * EB + ub) * (2 * H_ENC) + dir * H_ENC + ue] = c;
}

// ---------------- Decoder (R8 verbatim, verified ~250us: RELAXED flags) ----------------
#define DB 16
__global__ __launch_bounds__(512, 2)
void decoder_split(
    const float* __restrict__ Wih,   // [1024]
    const float* __restrict__ bb,    // [1024]
    const float* __restrict__ outW,  // [256]
    const float* __restrict__ outb,  // [1]
    const float* __restrict__ h0,    // [B,256]
    const float* __restrict__ c0,    // [B,256]
    const float* __restrict__ Whh,   // [1024,256]
    unsigned* __restrict__ hx,       // [2][1024][128] u32 (f16 pairs)
    int* __restrict__ cnt,           // [64][CNT_STRIDE]
    float* __restrict__ out)         // [B,T]
{
    const int blk = blockIdx.x;
    const int bg  = blk & 63;
    const int q   = blk >> 6;
    const int t   = threadIdx.x;
    const int w   = t >> 6;
    const int l   = t & 63;
    const int col = l & 15;
    const int grp = l >> 4;
    const int u   = w >> 1;
    const int fo  = w & 1;

    __shared__ unsigned hlU[DB][132];
    __shared__ float    exch[4][2][DB][16];
    __shared__ unsigned hnewU[DB][32];
    __shared__ float    yl[DB];
    __shared__ float    owl[H_DEC];
    int* mycnt = cnt + bg * CNT_STRIDE;

    if (t < H_DEC) owl[t] = outW[t];

    const int j0 = 64 * q + 16 * u + col;
    const int rA = (fo ? 256 : 0) + j0;
    const int rB = (fo ? 768 : 512) + j0;

    half8 wfA[8], wfB[8];
    #pragma unroll
    for (int kt = 0; kt < 8; ++kt) {
        const float* pa = Whh + (size_t)rA * H_DEC + 32 * kt + 8 * grp;
        const float* pb = Whh + (size_t)rB * H_DEC + 32 * kt + 8 * grp;
        float4 a0 = *reinterpret_cast<const float4*>(pa);
        float4 a1 = *reinterpret_cast<const float4*>(pa + 4);
        float4 b0 = *reinterpret_cast<const float4*>(pb);
        float4 b1 = *reinterpret_cast<const float4*>(pb + 4);
        half8 ha, hb;
        ha[0]=(_Float16)a0.x; ha[1]=(_Float16)a0.y; ha[2]=(_Float16)a0.z; ha[3]=(_Float16)a0.w;
        ha[4]=(_Float16)a1.x; ha[5]=(_Float16)a1.y; ha[6]=(_Float16)a1.z; ha[7]=(_Float16)a1.w;
        hb[0]=(_Float16)b0.x; hb[1]=(_Float16)b0.y; hb[2]=(_Float16)b0.z; hb[3]=(_Float16)b0.w;
        hb[4]=(_Float16)b1.x; hb[5]=(_Float16)b1.y; hb[6]=(_Float16)b1.z; hb[7]=(_Float16)b1.w;
        wfA[kt] = ha; wfB[kt] = hb;
    }

    const float bI = bb[j0],       wI = Wih[j0];
    const float bF = bb[256 + j0], wF = Wih[256 + j0];
    const float bG = bb[512 + j0], wG = Wih[512 + j0];
    const float bO = bb[768 + j0], wO = Wih[768 + j0];
    const float ob = outb[0];

    float c[4];
    #pragma unroll
    for (int r = 0; r < 4; ++r)
        c[r] = c0[(size_t)(bg * DB + 4 * grp + r) * H_DEC + j0];

    {
        int batch = t >> 5, pair = t & 31;
        int e = 64 * q + 2 * pair;
        const float* hp = h0 + (size_t)(bg * DB + batch) * H_DEC + e;
        unsigned v = packu(hp[0], hp[1]);
        __hip_atomic_store(&hx[(size_t)(bg * DB + batch) * 128 + 32 * q + pair], v,
                           __ATOMIC_RELAXED, __HIP_MEMORY_SCOPE_AGENT);
    }
    __syncthreads();   // drains vmcnt: stores ack'd at LLC before flag
    if (t == 0) {
        __hip_atomic_fetch_add(&mycnt[0], 1, __ATOMIC_RELAXED, __HIP_MEMORY_SCOPE_AGENT);
        while (__hip_atomic_load(&mycnt[0], __ATOMIC_RELAXED, __HIP_MEMORY_SCOPE_AGENT) < 4)
            __builtin_amdgcn_s_sleep(1);
    }
    __syncthreads();

    for (int s = 1; s <= T_DEC; ++s) {
        const int rb = (s - 1) & 1, wb = s & 1;
        #pragma unroll
        for (int i = 0; i < 4; ++i) {
            int j = t + 512 * i;
            int batch = j >> 7, within = j & 127;
            unsigned v = __hip_atomic_load(
                &hx[(size_t)rb * (B_TOT * 128) + (size_t)(bg * DB + batch) * 128 + within],
                __ATOMIC_RELAXED, __HIP_MEMORY_SCOPE_AGENT);
            hlU[batch][within] = v;
        }
        __syncthreads();

        {
            int batch = t >> 5, seg = t & 31;
            half8 hv = *reinterpret_cast<const half8*>(
                reinterpret_cast<const char*>(hlU) + batch * 528 + seg * 16);
            float sum = 0.f;
            #pragma unroll
            for (int j = 0; j < 8; ++j) sum += (float)hv[j] * owl[8 * seg + j];
            #pragma unroll
            for (int m = 1; m < 32; m <<= 1) sum += __shfl_xor(sum, m);
            if (seg == 0) {
                float yv = sum + ob;
                yl[batch] = (s == 1) ? 0.f : yv;
                if (q == 0 && s >= 2) out[(size_t)(bg * DB + batch) * T_DEC + (s - 2)] = yv;
            }
        }

        half8 a[8];
        #pragma unroll
        for (int kt = 0; kt < 8; ++kt)
            a[kt] = *reinterpret_cast<const half8*>(
                reinterpret_cast<const char*>(hlU) + col * 528 + (32 * kt + 8 * grp) * 2);

        f32x4 accA = {0.f, 0.f, 0.f, 0.f};
        f32x4 accB = {0.f, 0.f, 0.f, 0.f};
        #pragma unroll
        for (int kt = 0; kt < 8; ++kt) {
            accA = MFMA16(a[kt], wfA[kt], accA);
            accB = MFMA16(a[kt], wfB[kt], accB);
        }

        if (fo) {
            #pragma unroll
            for (int r = 0; r < 4; ++r) {
                exch[u][0][4 * grp + r][col] = accA[r] + bF;
                exch[u][1][4 * grp + r][col] = accB[r] + bO;
            }
        }
        __syncthreads();

        if (!fo) {
            #pragma unroll
            for (int r = 0; r < 4; ++r) {
                float yb = yl[4 * grp + r];
                float gi = sigmoidf_(accA[r] + bI + wI * yb);
                float gg = tanhf_  (accB[r] + bG + wG * yb);
                float gf = sigmoidf_(exch[u][0][4 * grp + r][col] + wF * yb);
                float go = sigmoidf_(exch[u][1][4 * grp + r][col] + wO * yb);
                c[r] = gf * c[r] + gi * gg;
                float h = go * tanhf_(c[r]);
                reinterpret_cast<_Float16*>(hnewU)[(4 * grp + r) * 64 + 16 * u + col] = (_Float16)h;
            }
        }
        __syncthreads();

        {
            int batch = t >> 5, pair = t & 31;
            __hip_atomic_store(
                &hx[(size_t)wb * (B_TOT * 128) + (size_t)(bg * DB + batch) * 128 + 32 * q + pair],
                hnewU[batch][pair], __ATOMIC_RELAXED, __HIP_MEMORY_SCOPE_AGENT);
        }
        __syncthreads();   // drains vmcnt before flag
        if (t == 0) {
            __hip_atomic_fetch_add(&mycnt[s], 1, __ATOMIC_RELAXED, __HIP_MEMORY_SCOPE_AGENT);
            while (__hip_atomic_load(&mycnt[s], __ATOMIC_RELAXED, __HIP_MEMORY_SCOPE_AGENT) < 4)
                __builtin_amdgcn_s_sleep(1);
        }
        __syncthreads();
    }

    {
        #pragma unroll
        for (int i = 0; i < 4; ++i) {
            int j = t + 512 * i;
            int batch = j >> 7, within = j & 127;
            unsigned v = __hip_atomic_load(
                &hx[(size_t)(bg * DB + batch) * 128 + within],
                __ATOMIC_RELAXED, __HIP_MEMORY_SCOPE_AGENT);
            hlU[batch][within] = v;
        }
        __syncthreads();
        int batch = t >> 5, seg = t & 31;
        half8 hv = *reinterpret_cast<const half8*>(
            reinterpret_cast<const char*>(hlU) + batch * 528 + seg * 16);
        float sum = 0.f;
        #pragma unroll
        for (int j = 0; j < 8; ++j) sum += (float)hv[j] * owl[8 * seg + j];
        #pragma unroll
        for (int m = 1; m < 32; m <<= 1) sum += __shfl_xor(sum, m);
        if (q == 0 && seg == 0)
            out[(size_t)(bg * DB + batch) * T_DEC + (T_DEC - 1)] = sum + ob;
    }
}

extern "C" void kernel_launch(void* const* d_in, const int* in_sizes, int n_in,
                              void* d_out, int out_size, void* d_ws, size_t ws_size,
                              hipStream_t stream) {
    const float* source = (const float*)d_in[0];
    const float* eWih_f = (const float*)d_in[2];
    const float* eWhh_f = (const float*)d_in[3];
    const float* eb_f   = (const float*)d_in[4];
    const float* eWih_b = (const float*)d_in[5];
    const float* eWhh_b = (const float*)d_in[6];
    const float* eb_b   = (const float*)d_in[7];
    const float* dWih   = (const float*)d_in[8];
    const float* dWhh   = (const float*)d_in[9];
    const float* db     = (const float*)d_in[10];
    const float* oW     = (const float*)d_in[11];
    const float* obp    = (const float*)d_in[12];
    float* out = (float*)d_out;

    float*    h0  = (float*)d_ws;                             // 1 MB
    float*    c0  = h0 + (size_t)B_TOT * H_DEC;               // 1 MB
    unsigned* hx  = (unsigned*)(c0 + (size_t)B_TOT * H_DEC);  // 1 MB
    int*      cnt = (int*)(hx + (size_t)2 * B_TOT * 128);     // 64*104 ints

    zero_cnt<<<(64 * CNT_STRIDE + 255) / 256, 256, 0, stream>>>(cnt);
    encoder_eb8<<<128 * 2, 1024, 0, stream>>>(
        source, eWih_f, eWhh_f, eb_f, eWih_b, eWhh_b, eb_b, h0, c0);
    decoder_split<<<256, 512, 0, stream>>>(   // literal 256: 64 groups x 4 chunks
        dWih, db, oW, obp, h0, c0, dWhh, hx, cnt, out);
}

// Round 13
// 768.761 us; speedup vs baseline: 1.8751x; 1.0031x over previous
//
#include <hip/hip_runtime.h>
#include <math.h>

#define H_ENC 128
#define H_DEC 256
#define L_SRC 512
#define T_DEC 96
#define B_TOT 1024

typedef _Float16 half8 __attribute__((ext_vector_type(8)));
typedef float f32x4 __attribute__((ext_vector_type(4)));

#define MFMA16(A, B, C) __builtin_amdgcn_mfma_f32_16x16x32_f16((A), (B), (C), 0, 0, 0)

__device__ __forceinline__ unsigned packu(float a, float b) {
    union { _Float16 h[2]; unsigned u; } x; x.h[0] = (_Float16)a; x.h[1] = (_Float16)b; return x.u;
}

// division/clamp-free (NaN-safe at +-inf)
__device__ __forceinline__ float sigmoidf_(float x) {
    return __builtin_amdgcn_rcpf(1.f + __expf(-x));
}
__device__ __forceinline__ float tanhf_(float x) {
    return 1.f - 2.f * __builtin_amdgcn_rcpf(__expf(2.f * x) + 1.f);
}

// ---------------- flag init (fresh every launch: graph-replay safe) ----------------
#define CNT_STRIDE 104
__global__ void zero_cnt(int* cnt) {
    int i = blockIdx.x * blockDim.x + threadIdx.x;
    if (i < 64 * CNT_STRIDE) cnt[i] = 0;
}

// ---------------- Encoder v9: R12 structure, setprio REMOVED (m190: hurts lockstep) ----------------
#define EB 8
#define HPAD 136
__global__ __launch_bounds__(1024)
void encoder_eb8(
    const float* __restrict__ source,
    const float* __restrict__ Wih_f, const float* __restrict__ Whh_f, const float* __restrict__ b_f,
    const float* __restrict__ Wih_b, const float* __restrict__ Whh_b, const float* __restrict__ b_b,
    float* __restrict__ h0, float* __restrict__ c0)
{
    const int dir = blockIdx.x & 1;
    const int bg  = blockIdx.x >> 1;       // 0..127
    const int t   = threadIdx.x;           // 0..1023
    const int w   = t >> 6;                // wave 0..15
    const int l   = t & 63;
    const int col = l & 15;
    const int grp = l >> 4;

    const float* Wih = dir ? Wih_b : Wih_f;
    const float* Whh = dir ? Whh_b : Whh_f;
    const float* bb  = dir ? b_b   : b_f;

    __shared__ float    xsT[L_SRC][EB];        // 16 KB [step][batch]
    __shared__ _Float16 hbuf[2][EB][HPAD];     // 4.3 KB double-buffered
    __shared__ float    gbuf[4][EB][H_ENC];    // 16 KB raw gates [gate][batch][elem]

    {
        const float* srcb = source + (size_t)bg * EB * L_SRC;
        for (int i = t; i < EB * L_SRC; i += 1024) {
            int b = i >> 9, st = i & 511;
            xsT[st][b] = srcb[i];              // coalesced global read
        }
        for (int i = t; i < 2 * EB * HPAD; i += 1024)
            ((_Float16*)hbuf)[i] = (_Float16)0.f;
    }

    // B-frags for my 2 tiles (n = 2w+tau); bias folded into acc init.
    half8 wf[2][4];
    float bias2[2];
    #pragma unroll
    for (int tau = 0; tau < 2; ++tau) {
        const int n = 2 * w + tau;
        const int grow = (n >> 3) * H_ENC + 16 * (n & 7) + col;
        bias2[tau] = bb[grow];
        const float* wr = Whh + (size_t)grow * H_ENC;
        #pragma unroll
        for (int kt = 0; kt < 4; ++kt) {
            const float* p = wr + 32 * kt + 8 * grp;
            float4 v0 = *reinterpret_cast<const float4*>(p);
            float4 v1 = *reinterpret_cast<const float4*>(p + 4);
            half8 h;
            h[0] = (_Float16)v0.x; h[1] = (_Float16)v0.y; h[2] = (_Float16)v0.z; h[3] = (_Float16)v0.w;
            h[4] = (_Float16)v1.x; h[5] = (_Float16)v1.y; h[6] = (_Float16)v1.z; h[7] = (_Float16)v1.w;
            wf[tau][kt] = h;
        }
    }

    // phase-3 identity: one (batch, elem) per lane
    const int ub = t >> 7;                 // batch 0..7
    const int ue = t & 127;                // h-elem 0..127
    const float wI = Wih[ue];
    const float wF = Wih[H_ENC + ue];
    const float wG = Wih[2*H_ENC + ue];
    const float wO = Wih[3*H_ENC + ue];

    float c = 0.f, hlast = 0.f;
    __syncthreads();

    int cur = 0;
    for (int s = 0; s < L_SRC; ++s) {
        const int step = dir ? (L_SRC - 1 - s) : s;

        // ---- phase 1: MFMA; A-cols 0..7 = batches, rest zero ----
        half8 a0 = {0,0,0,0,0,0,0,0}, a1 = a0, a2 = a0, a3 = a0;
        if (col < EB) {
            a0 = *reinterpret_cast<const half8*>(&hbuf[cur][col][ 0 + 8 * grp]);
            a1 = *reinterpret_cast<const half8*>(&hbuf[cur][col][32 + 8 * grp]);
            a2 = *reinterpret_cast<const half8*>(&hbuf[cur][col][64 + 8 * grp]);
            a3 = *reinterpret_cast<const half8*>(&hbuf[cur][col][96 + 8 * grp]);
        }

        f32x4 acc0 = {bias2[0], bias2[0], bias2[0], bias2[0]};
        f32x4 acc1 = {bias2[1], bias2[1], bias2[1], bias2[1]};
        acc0 = MFMA16(a0, wf[0][0], acc0); acc0 = MFMA16(a1, wf[0][1], acc0);
        acc0 = MFMA16(a2, wf[0][2], acc0); acc0 = MFMA16(a3, wf[0][3], acc0);
        acc1 = MFMA16(a0, wf[1][0], acc1); acc1 = MFMA16(a1, wf[1][1], acc1);
        acc1 = MFMA16(a2, wf[1][2], acc1); acc1 = MFMA16(a3, wf[1][3], acc1);

        // ---- phase 2: valid C rows (batch = 4*grp+r < 8 -> grp<2) -> gbuf ----
        if (grp < 2) {
            #pragma unroll
            for (int tau = 0; tau < 2; ++tau) {
                const int n = 2 * w + tau;
                const int G = n >> 3;
                const int e = 16 * (n & 7) + col;
                const f32x4 acc = tau ? acc1 : acc0;
                #pragma unroll
                for (int r = 0; r < 4; ++r)
                    gbuf[G][4 * grp + r][e] = acc[r];
            }
        }
        __syncthreads();

        // ---- phase 3: one LSTM update per lane (bias already in gbuf) ----
        {
            float x = xsT[step][ub];
            float gi = sigmoidf_(gbuf[0][ub][ue] + wI * x);
            float gf = sigmoidf_(gbuf[1][ub][ue] + wF * x);
            float gg = tanhf_  (gbuf[2][ub][ue] + wG * x);
            float go = sigmoidf_(gbuf[3][ub][ue] + wO * x);
            c = gf * c + gi * gg;
            float h = go * tanhf_(c);
            hlast = h;
            hbuf[cur ^ 1][ub][ue] = (_Float16)h;
        }
        __syncthreads();
        cur ^= 1;
    }

    h0[(size_t)(bg * EB + ub) * (2 * H_ENC) + dir * H_ENC + ue] = hlast;
    c0[(size_t)(bg * EB + ub) * (2 * H_ENC) + dir * H_ENC + ue] = c;
}

// ---------------- Decoder (R8 verbatim, verified ~250us: RELAXED flags) ----------------
#define DB 16
__global__ __launch_bounds__(512, 2)
void decoder_split(
    const float* __restrict__ Wih,   // [1024]
    const float* __restrict__ bb,    // [1024]
    const float* __restrict__ outW,  // [256]
    const float* __restrict__ outb,  // [1]
    const float* __restrict__ h0,    // [B,256]
    const float* __restrict__ c0,    // [B,256]
    const float* __restrict__ Whh,   // [1024,256]
    unsigned* __restrict__ hx,       // [2][1024][128] u32 (f16 pairs)
    int* __restrict__ cnt,           // [64][CNT_STRIDE]
    float* __restrict__ out)         // [B,T]
{
    const int blk = blockIdx.x;
    const int bg  = blk & 63;
    const int q   = blk >> 6;
    const int t   = threadIdx.x;
    const int w   = t >> 6;
    const int l   = t & 63;
    const int col = l & 15;
    const int grp = l >> 4;
    const int u   = w >> 1;
    const int fo  = w & 1;

    __shared__ unsigned hlU[DB][132];
    __shared__ float    exch[4][2][DB][16];
    __shared__ unsigned hnewU[DB][32];
    __shared__ float    yl[DB];
    __shared__ float    owl[H_DEC];
    int* mycnt = cnt + bg * CNT_STRIDE;

    if (t < H_DEC) owl[t] = outW[t];

    const int j0 = 64 * q + 16 * u + col;
    const int rA = (fo ? 256 : 0) + j0;
    const int rB = (fo ? 768 : 512) + j0;

    half8 wfA[8], wfB[8];
    #pragma unroll
    for (int kt = 0; kt < 8; ++kt) {
        const float* pa = Whh + (size_t)rA * H_DEC + 32 * kt + 8 * grp;
        const float* pb = Whh + (size_t)rB * H_DEC + 32 * kt + 8 * grp;
        float4 a0 = *reinterpret_cast<const float4*>(pa);
        float4 a1 = *reinterpret_cast<const float4*>(pa + 4);
        float4 b0 = *reinterpret_cast<const float4*>(pb);
        float4 b1 = *reinterpret_cast<const float4*>(pb + 4);
        half8 ha, hb;
        ha[0]=(_Float16)a0.x; ha[1]=(_Float16)a0.y; ha[2]=(_Float16)a0.z; ha[3]=(_Float16)a0.w;
        ha[4]=(_Float16)a1.x; ha[5]=(_Float16)a1.y; ha[6]=(_Float16)a1.z; ha[7]=(_Float16)a1.w;
        hb[0]=(_Float16)b0.x; hb[1]=(_Float16)b0.y; hb[2]=(_Float16)b0.z; hb[3]=(_Float16)b0.w;
        hb[4]=(_Float16)b1.x; hb[5]=(_Float16)b1.y; hb[6]=(_Float16)b1.z; hb[7]=(_Float16)b1.w;
        wfA[kt] = ha; wfB[kt] = hb;
    }

    const float bI = bb[j0],       wI = Wih[j0];
    const float bF = bb[256 + j0], wF = Wih[256 + j0];
    const float bG = bb[512 + j0], wG = Wih[512 + j0];
    const float bO = bb[768 + j0], wO = Wih[768 + j0];
    const float ob = outb[0];

    float c[4];
    #pragma unroll
    for (int r = 0; r < 4; ++r)
        c[r] = c0[(size_t)(bg * DB + 4 * grp + r) * H_DEC + j0];

    {
        int batch = t >> 5, pair = t & 31;
        int e = 64 * q + 2 * pair;
        const float* hp = h0 + (size_t)(bg * DB + batch) * H_DEC + e;
        unsigned v = packu(hp[0], hp[1]);
        __hip_atomic_store(&hx[(size_t)(bg * DB + batch) * 128 + 32 * q + pair], v,
                           __ATOMIC_RELAXED, __HIP_MEMORY_SCOPE_AGENT);
    }
    __syncthreads();   // drains vmcnt: stores ack'd at LLC before flag
    if (t == 0) {
        __hip_atomic_fetch_add(&mycnt[0], 1, __ATOMIC_RELAXED, __HIP_MEMORY_SCOPE_AGENT);
        while (__hip_atomic_load(&mycnt[0], __ATOMIC_RELAXED, __HIP_MEMORY_SCOPE_AGENT) < 4)
            __builtin_amdgcn_s_sleep(1);
    }
    __syncthreads();

    for (int s = 1; s <= T_DEC; ++s) {
        const int rb = (s - 1) & 1, wb = s & 1;
        #pragma unroll
        for (int i = 0; i < 4; ++i) {
            int j = t + 512 * i;
            int batch = j >> 7, within = j & 127;
            unsigned v = __hip_atomic_load(
                &hx[(size_t)rb * (B_TOT * 128) + (size_t)(bg * DB + batch) * 128 + within],
                __ATOMIC_RELAXED, __HIP_MEMORY_SCOPE_AGENT);
            hlU[batch][within] = v;
        }
        __syncthreads();

        {
            int batch = t >> 5, seg = t & 31;
            half8 hv = *reinterpret_cast<const half8*>(
                reinterpret_cast<const char*>(hlU) + batch * 528 + seg * 16);
            float sum = 0.f;
            #pragma unroll
            for (int j = 0; j < 8; ++j) sum += (float)hv[j] * owl[8 * seg + j];
            #pragma unroll
            for (int m = 1; m < 32; m <<= 1) sum += __shfl_xor(sum, m);
            if (seg == 0) {
                float yv = sum + ob;
                yl[batch] = (s == 1) ? 0.f : yv;
                if (q == 0 && s >= 2) out[(size_t)(bg * DB + batch) * T_DEC + (s - 2)] = yv;
            }
        }

        half8 a[8];
        #pragma unroll
        for (int kt = 0; kt < 8; ++kt)
            a[kt] = *reinterpret_cast<const half8*>(
                reinterpret_cast<const char*>(hlU) + col * 528 + (32 * kt + 8 * grp) * 2);

        f32x4 accA = {0.f, 0.f, 0.f, 0.f};
        f32x4 accB = {0.f, 0.f, 0.f, 0.f};
        #pragma unroll
        for (int kt = 0; kt < 8; ++kt) {
            accA = MFMA16(a[kt], wfA[kt], accA);
            accB = MFMA16(a[kt], wfB[kt], accB);
        }

        if (fo) {
            #pragma unroll
            for (int r = 0; r < 4; ++r) {
                exch[u][0][4 * grp + r][col] = accA[r] + bF;
                exch[u][1][4 * grp + r][col] = accB[r] + bO;
            }
        }
        __syncthreads();

        if (!fo) {
            #pragma unroll
            for (int r = 0; r < 4; ++r) {
                float yb = yl[4 * grp + r];
                float gi = sigmoidf_(accA[r] + bI + wI * yb);
                float gg = tanhf_  (accB[r] + bG + wG * yb);
                float gf = sigmoidf_(exch[u][0][4 * grp + r][col] + wF * yb);
                float go = sigmoidf_(exch[u][1][4 * grp + r][col] + wO * yb);
                c[r] = gf * c[r] + gi * gg;
                float h = go * tanhf_(c[r]);
                reinterpret_cast<_Float16*>(hnewU)[(4 * grp + r) * 64 + 16 * u + col] = (_Float16)h;
            }
        }
        __syncthreads();

        {
            int batch = t >> 5, pair = t & 31;
            __hip_atomic_store(
                &hx[(size_t)wb * (B_TOT * 128) + (size_t)(bg * DB + batch) * 128 + 32 * q + pair],
                hnewU[batch][pair], __ATOMIC_RELAXED, __HIP_MEMORY_SCOPE_AGENT);
        }
        __syncthreads();   // drains vmcnt before flag
        if (t == 0) {
            __hip_atomic_fetch_add(&mycnt[s], 1, __ATOMIC_RELAXED, __HIP_MEMORY_SCOPE_AGENT);
            while (__hip_atomic_load(&mycnt[s], __ATOMIC_RELAXED, __HIP_MEMORY_SCOPE_AGENT) < 4)
                __builtin_amdgcn_s_sleep(1);
        }
        __syncthreads();
    }

    {
        #pragma unroll
        for (int i = 0; i < 4; ++i) {
            int j = t + 512 * i;
            int batch = j >> 7, within = j & 127;
            unsigned v = __hip_atomic_load(
                &hx[(size_t)(bg * DB + batch) * 128 + within],
                __ATOMIC_RELAXED, __HIP_MEMORY_SCOPE_AGENT);
            hlU[batch][within] = v;
        }
        __syncthreads();
        int batch = t >> 5, seg = t & 31;
        half8 hv = *reinterpret_cast<const half8*>(
            reinterpret_cast<const char*>(hlU) + batch * 528 + seg * 16);
        float sum = 0.f;
        #pragma unroll
        for (int j = 0; j < 8; ++j) sum += (float)hv[j] * owl[8 * seg + j];
        #pragma unroll
        for (int m = 1; m < 32; m <<= 1) sum += __shfl_xor(sum, m);
        if (q == 0 && seg == 0)
            out[(size_t)(bg * DB + batch) * T_DEC + (T_DEC - 1)] = sum + ob;
    }
}

extern "C" void kernel_launch(void* const* d_in, const int* in_sizes, int n_in,
                              void* d_out, int out_size, void* d_ws, size_t ws_size,
                              hipStream_t stream) {
    const float* source = (const float*)d_in[0];
    const float* eWih_f = (const float*)d_in[2];
    const float* eWhh_f = (const float*)d_in[3];
    const float* eb_f   = (const float*)d_in[4];
    const float* eWih_b = (const float*)d_in[5];
    const float* eWhh_b = (const float*)d_in[6];
    const float* eb_b   = (const float*)d_in[7];
    const float* dWih   = (const float*)d_in[8];
    const float* dWhh   = (const float*)d_in[9];
    const float* db     = (const float*)d_in[10];
    const float* oW     = (const float*)d_in[11];
    const float* obp    = (const float*)d_in[12];
    float* out = (float*)d_out;

    float*    h0  = (float*)d_ws;                             // 1 MB
    float*    c0  = h0 + (size_t)B_TOT * H_DEC;               // 1 MB
    unsigned* hx  = (unsigned*)(c0 + (size_t)B_TOT * H_DEC);  // 1 MB
    int*      cnt = (int*)(hx + (size_t)2 * B_TOT * 128);     // 64*104 ints

    zero_cnt<<<(64 * CNT_STRIDE + 255) / 256, 256, 0, stream>>>(cnt);
    encoder_eb8<<<128 * 2, 1024, 0, stream>>>(
        source, eWih_f, eWhh_f, eb_f, eWih_b, eWhh_b, eb_b, h0, c0);
    decoder_split<<<256, 512, 0, stream>>>(   // literal 256: 64 groups x 4 chunks
        dWih, db, oW, obp, h0, c0, dWhh, hx, cnt, out);
}

// Round 14
// 743.367 us; speedup vs baseline: 1.9391x; 1.0342x over previous
//
#include <hip/hip_runtime.h>
#include <math.h>

#define H_ENC 128
#define H_DEC 256
#define L_SRC 512
#define T_DEC 96
#define B_TOT 1024

typedef _Float16 half8 __attribute__((ext_vector_type(8)));
typedef float f32x4 __attribute__((ext_vector_type(4)));

#define MFMA16(A, B, C) __builtin_amdgcn_mfma_f32_16x16x32_f16((A), (B), (C), 0, 0, 0)

__device__ __forceinline__ unsigned packu(float a, float b) {
    union { _Float16 h[2]; unsigned u; } x; x.h[0] = (_Float16)a; x.h[1] = (_Float16)b; return x.u;
}

// division/clamp-free (NaN-safe at +-inf)
__device__ __forceinline__ float sigmoidf_(float x) {
    return __builtin_amdgcn_rcpf(1.f + __expf(-x));
}
__device__ __forceinline__ float tanhf_(float x) {
    return 1.f - 2.f * __builtin_amdgcn_rcpf(__expf(2.f * x) + 1.f);
}

// ---------------- flag init (fresh every launch: graph-replay safe) ----------------
#define CNT_STRIDE 104
__global__ void zero_cnt(int* cnt) {
    int i = blockIdx.x * blockDim.x + threadIdx.x;
    if (i < 64 * CNT_STRIDE) cnt[i] = 0;
}

// ---------------- Encoder v10: in-wave gate redistribute, 1 barrier/step ----------------
// EB=8, 512 thr (8 waves), grid = 128*2 = 256 blocks. Wave w owns ALL 4 gate
// tiles (i,f,g,o) for elems [16w,16w+16) -> after MFMA the full gate set is
// in-wave. __shfl redistribution (16 bpermute + 8 select) hands lane (col,grp)
// batches {4*(l>=32)+2*(grp&1), +1}: 2 updates/lane, zero masked trans, no
// gbuf, ONE barrier per step (hbuf publish).
#define EB 8
#define HPAD 136
__global__ __launch_bounds__(512)
void encoder_swz(
    const float* __restrict__ source,
    const float* __restrict__ Wih_f, const float* __restrict__ Whh_f, const float* __restrict__ b_f,
    const float* __restrict__ Wih_b, const float* __restrict__ Whh_b, const float* __restrict__ b_b,
    float* __restrict__ h0, float* __restrict__ c0)
{
    const int dir = blockIdx.x & 1;
    const int bg  = blockIdx.x >> 1;       // 0..127
    const int t   = threadIdx.x;           // 0..511
    const int w   = t >> 6;                // wave 0..7
    const int l   = t & 63;
    const int col = l & 15;
    const int grp = l >> 4;

    const float* Wih = dir ? Wih_b : Wih_f;
    const float* Whh = dir ? Whh_b : Whh_f;
    const float* bb  = dir ? b_b   : b_f;

    __shared__ float    xsT[L_SRC][EB];        // 16 KB [step][batch]
    __shared__ _Float16 hbuf[2][EB][HPAD];     // 4.3 KB double-buffered

    {
        const float* srcb = source + (size_t)bg * EB * L_SRC;
        for (int i = t; i < EB * L_SRC; i += 512) {
            int b = i >> 9, st = i & 511;
            xsT[st][b] = srcb[i];              // coalesced global read
        }
        for (int i = t; i < 2 * EB * HPAD; i += 512)
            ((_Float16*)hbuf)[i] = (_Float16)0.f;
    }

    const int e = 16 * w + col;                // my elem 0..127

    // B-frags: gate tt (i,f,g,o), Whh row = tt*128 + e; bias folded into acc.
    half8 wf[4][4];
    float bias4[4];
    #pragma unroll
    for (int tt = 0; tt < 4; ++tt) {
        const int grow = tt * H_ENC + e;
        bias4[tt] = bb[grow];
        const float* wr = Whh + (size_t)grow * H_ENC;
        #pragma unroll
        for (int kt = 0; kt < 4; ++kt) {
            const float* p = wr + 32 * kt + 8 * grp;
            float4 v0 = *reinterpret_cast<const float4*>(p);
            float4 v1 = *reinterpret_cast<const float4*>(p + 4);
            half8 h;
            h[0] = (_Float16)v0.x; h[1] = (_Float16)v0.y; h[2] = (_Float16)v0.z; h[3] = (_Float16)v0.w;
            h[4] = (_Float16)v1.x; h[5] = (_Float16)v1.y; h[6] = (_Float16)v1.z; h[7] = (_Float16)v1.w;
            wf[tt][kt] = h;
        }
    }

    // update identity: this lane owns batches bA,bB at elem e
    const int par  = grp & 1;
    const int half = l >> 5;
    const int bA   = 4 * half + 2 * par;
    const int bB   = bA + 1;
    const int src  = col + (half << 4);    // shfl source lane (grp0 or grp1)

    const float wI = Wih[e];
    const float wF = Wih[H_ENC + e];
    const float wG = Wih[2 * H_ENC + e];
    const float wO = Wih[3 * H_ENC + e];

    float cA = 0.f, cB = 0.f, hAl = 0.f, hBl = 0.f;
    __syncthreads();

    int cur = 0;
    for (int s = 0; s < L_SRC; ++s) {
        const int step = dir ? (L_SRC - 1 - s) : s;

        // ---- MFMA: A-cols 0..7 = batches, rest zero ----
        half8 a0 = {0,0,0,0,0,0,0,0}, a1 = a0, a2 = a0, a3 = a0;
        if (col < EB) {
            a0 = *reinterpret_cast<const half8*>(&hbuf[cur][col][ 0 + 8 * grp]);
            a1 = *reinterpret_cast<const half8*>(&hbuf[cur][col][32 + 8 * grp]);
            a2 = *reinterpret_cast<const half8*>(&hbuf[cur][col][64 + 8 * grp]);
            a3 = *reinterpret_cast<const half8*>(&hbuf[cur][col][96 + 8 * grp]);
        }

        f32x4 acc0 = {bias4[0], bias4[0], bias4[0], bias4[0]};   // i
        f32x4 acc1 = {bias4[1], bias4[1], bias4[1], bias4[1]};   // f
        f32x4 acc2 = {bias4[2], bias4[2], bias4[2], bias4[2]};   // g
        f32x4 acc3 = {bias4[3], bias4[3], bias4[3], bias4[3]};   // o
        acc0 = MFMA16(a0, wf[0][0], acc0); acc0 = MFMA16(a1, wf[0][1], acc0);
        acc0 = MFMA16(a2, wf[0][2], acc0); acc0 = MFMA16(a3, wf[0][3], acc0);
        acc1 = MFMA16(a0, wf[1][0], acc1); acc1 = MFMA16(a1, wf[1][1], acc1);
        acc1 = MFMA16(a2, wf[1][2], acc1); acc1 = MFMA16(a3, wf[1][3], acc1);
        acc2 = MFMA16(a0, wf[2][0], acc2); acc2 = MFMA16(a1, wf[2][1], acc2);
        acc2 = MFMA16(a2, wf[2][2], acc2); acc2 = MFMA16(a3, wf[2][3], acc2);
        acc3 = MFMA16(a0, wf[3][0], acc3); acc3 = MFMA16(a1, wf[3][1], acc3);
        acc3 = MFMA16(a2, wf[3][2], acc3); acc3 = MFMA16(a3, wf[3][3], acc3);

        // ---- in-wave redistribute: C row 4*g+r (batch) @ lane(col,g) -> owner lane ----
        // src lane holds batches {4*half + r} in reg r; pick 2*par, 2*par+1.
        float i0 = __shfl(acc0[0], src), i1 = __shfl(acc0[1], src),
              i2 = __shfl(acc0[2], src), i3 = __shfl(acc0[3], src);
        float f0 = __shfl(acc1[0], src), f1 = __shfl(acc1[1], src),
              f2 = __shfl(acc1[2], src), f3 = __shfl(acc1[3], src);
        float g0 = __shfl(acc2[0], src), g1 = __shfl(acc2[1], src),
              g2 = __shfl(acc2[2], src), g3 = __shfl(acc2[3], src);
        float o0 = __shfl(acc3[0], src), o1 = __shfl(acc3[1], src),
              o2 = __shfl(acc3[2], src), o3 = __shfl(acc3[3], src);
        float iA = par ? i2 : i0, iB = par ? i3 : i1;
        float fA = par ? f2 : f0, fB = par ? f3 : f1;
        float gA = par ? g2 : g0, gB = par ? g3 : g1;
        float oA = par ? o2 : o0, oB = par ? o3 : o1;

        // ---- 2 LSTM updates per lane (all 512 lanes useful) ----
        {
            float xA = xsT[step][bA];
            float xB = xsT[step][bB];
            float giA = sigmoidf_(iA + wI * xA), giB = sigmoidf_(iB + wI * xB);
            float gfA = sigmoidf_(fA + wF * xA), gfB = sigmoidf_(fB + wF * xB);
            float ggA = tanhf_  (gA + wG * xA), ggB = tanhf_  (gB + wG * xB);
            float goA = sigmoidf_(oA + wO * xA), goB = sigmoidf_(oB + wO * xB);
            cA = gfA * cA + giA * ggA;
            cB = gfB * cB + giB * ggB;
            float hA = goA * tanhf_(cA);
            float hB = goB * tanhf_(cB);
            hAl = hA; hBl = hB;
            hbuf[cur ^ 1][bA][e] = (_Float16)hA;
            hbuf[cur ^ 1][bB][e] = (_Float16)hB;
        }
        __syncthreads();   // single barrier: new h visible
        cur ^= 1;
    }

    h0[(size_t)(bg * EB + bA) * (2 * H_ENC) + dir * H_ENC + e] = hAl;
    c0[(size_t)(bg * EB + bA) * (2 * H_ENC) + dir * H_ENC + e] = cA;
    h0[(size_t)(bg * EB + bB) * (2 * H_ENC) + dir * H_ENC + e] = hBl;
    c0[(size_t)(bg * EB + bB) * (2 * H_ENC) + dir * H_ENC + e] = cB;
}

// ---------------- Decoder (R8 verbatim, verified ~250us: RELAXED flags) ----------------
#define DB 16
__global__ __launch_bounds__(512, 2)
void decoder_split(
    const float* __restrict__ Wih,   // [1024]
    const float* __restrict__ bb,    // [1024]
    const float* __restrict__ outW,  // [256]
    const float* __restrict__ outb,  // [1]
    const float* __restrict__ h0,    // [B,256]
    const float* __restrict__ c0,    // [B,256]
    const float* __restrict__ Whh,   // [1024,256]
    unsigned* __restrict__ hx,       // [2][1024][128] u32 (f16 pairs)
    int* __restrict__ cnt,           // [64][CNT_STRIDE]
    float* __restrict__ out)         // [B,T]
{
    const int blk = blockIdx.x;
    const int bg  = blk & 63;
    const int q   = blk >> 6;
    const int t   = threadIdx.x;
    const int w   = t >> 6;
    const int l   = t & 63;
    const int col = l & 15;
    const int grp = l >> 4;
    const int u   = w >> 1;
    const int fo  = w & 1;

    __shared__ unsigned hlU[DB][132];
    __shared__ float    exch[4][2][DB][16];
    __shared__ unsigned hnewU[DB][32];
    __shared__ float    yl[DB];
    __shared__ float    owl[H_DEC];
    int* mycnt = cnt + bg * CNT_STRIDE;

    if (t < H_DEC) owl[t] = outW[t];

    const int j0 = 64 * q + 16 * u + col;
    const int rA = (fo ? 256 : 0) + j0;
    const int rB = (fo ? 768 : 512) + j0;

    half8 wfA[8], wfB[8];
    #pragma unroll
    for (int kt = 0; kt < 8; ++kt) {
        const float* pa = Whh + (size_t)rA * H_DEC + 32 * kt + 8 * grp;
        const float* pb = Whh + (size_t)rB * H_DEC + 32 * kt + 8 * grp;
        float4 a0 = *reinterpret_cast<const float4*>(pa);
        float4 a1 = *reinterpret_cast<const float4*>(pa + 4);
        float4 b0 = *reinterpret_cast<const float4*>(pb);
        float4 b1 = *reinterpret_cast<const float4*>(pb + 4);
        half8 ha, hb;
        ha[0]=(_Float16)a0.x; ha[1]=(_Float16)a0.y; ha[2]=(_Float16)a0.z; ha[3]=(_Float16)a0.w;
        ha[4]=(_Float16)a1.x; ha[5]=(_Float16)a1.y; ha[6]=(_Float16)a1.z; ha[7]=(_Float16)a1.w;
        hb[0]=(_Float16)b0.x; hb[1]=(_Float16)b0.y; hb[2]=(_Float16)b0.z; hb[3]=(_Float16)b0.w;
        hb[4]=(_Float16)b1.x; hb[5]=(_Float16)b1.y; hb[6]=(_Float16)b1.z; hb[7]=(_Float16)b1.w;
        wfA[kt] = ha; wfB[kt] = hb;
    }

    const float bI = bb[j0],       wI = Wih[j0];
    const float bF = bb[256 + j0], wF = Wih[256 + j0];
    const float bG = bb[512 + j0], wG = Wih[512 + j0];
    const float bO = bb[768 + j0], wO = Wih[768 + j0];
    const float ob = outb[0];

    float c[4];
    #pragma unroll
    for (int r = 0; r < 4; ++r)
        c[r] = c0[(size_t)(bg * DB + 4 * grp + r) * H_DEC + j0];

    {
        int batch = t >> 5, pair = t & 31;
        int e = 64 * q + 2 * pair;
        const float* hp = h0 + (size_t)(bg * DB + batch) * H_DEC + e;
        unsigned v = packu(hp[0], hp[1]);
        __hip_atomic_store(&hx[(size_t)(bg * DB + batch) * 128 + 32 * q + pair], v,
                           __ATOMIC_RELAXED, __HIP_MEMORY_SCOPE_AGENT);
    }
    __syncthreads();   // drains vmcnt: stores ack'd at LLC before flag
    if (t == 0) {
        __hip_atomic_fetch_add(&mycnt[0], 1, __ATOMIC_RELAXED, __HIP_MEMORY_SCOPE_AGENT);
        while (__hip_atomic_load(&mycnt[0], __ATOMIC_RELAXED, __HIP_MEMORY_SCOPE_AGENT) < 4)
            __builtin_amdgcn_s_sleep(1);
    }
    __syncthreads();

    for (int s = 1; s <= T_DEC; ++s) {
        const int rb = (s - 1) & 1, wb = s & 1;
        #pragma unroll
        for (int i = 0; i < 4; ++i) {
            int j = t + 512 * i;
            int batch = j >> 7, within = j & 127;
            unsigned v = __hip_atomic_load(
                &hx[(size_t)rb * (B_TOT * 128) + (size_t)(bg * DB + batch) * 128 + within],
                __ATOMIC_RELAXED, __HIP_MEMORY_SCOPE_AGENT);
            hlU[batch][within] = v;
        }
        __syncthreads();

        {
            int batch = t >> 5, seg = t & 31;
            half8 hv = *reinterpret_cast<const half8*>(
                reinterpret_cast<const char*>(hlU) + batch * 528 + seg * 16);
            float sum = 0.f;
            #pragma unroll
            for (int j = 0; j < 8; ++j) sum += (float)hv[j] * owl[8 * seg + j];
            #pragma unroll
            for (int m = 1; m < 32; m <<= 1) sum += __shfl_xor(sum, m);
            if (seg == 0) {
                float yv = sum + ob;
                yl[batch] = (s == 1) ? 0.f : yv;
                if (q == 0 && s >= 2) out[(size_t)(bg * DB + batch) * T_DEC + (s - 2)] = yv;
            }
        }

        half8 a[8];
        #pragma unroll
        for (int kt = 0; kt < 8; ++kt)
            a[kt] = *reinterpret_cast<const half8*>(
                reinterpret_cast<const char*>(hlU) + col * 528 + (32 * kt + 8 * grp) * 2);

        f32x4 accA = {0.f, 0.f, 0.f, 0.f};
        f32x4 accB = {0.f, 0.f, 0.f, 0.f};
        #pragma unroll
        for (int kt = 0; kt < 8; ++kt) {
            accA = MFMA16(a[kt], wfA[kt], accA);
            accB = MFMA16(a[kt], wfB[kt], accB);
        }

        if (fo) {
            #pragma unroll
            for (int r = 0; r < 4; ++r) {
                exch[u][0][4 * grp + r][col] = accA[r] + bF;
                exch[u][1][4 * grp + r][col] = accB[r] + bO;
            }
        }
        __syncthreads();

        if (!fo) {
            #pragma unroll
            for (int r = 0; r < 4; ++r) {
                float yb = yl[4 * grp + r];
                float gi = sigmoidf_(accA[r] + bI + wI * yb);
                float gg = tanhf_  (accB[r] + bG + wG * yb);
                float gf = sigmoidf_(exch[u][0][4 * grp + r][col] + wF * yb);
                float go = sigmoidf_(exch[u][1][4 * grp + r][col] + wO * yb);
                c[r] = gf * c[r] + gi * gg;
                float h = go * tanhf_(c[r]);
                reinterpret_cast<_Float16*>(hnewU)[(4 * grp + r) * 64 + 16 * u + col] = (_Float16)h;
            }
        }
        __syncthreads();

        {
            int batch = t >> 5, pair = t & 31;
            __hip_atomic_store(
                &hx[(size_t)wb * (B_TOT * 128) + (size_t)(bg * DB + batch) * 128 + 32 * q + pair],
                hnewU[batch][pair], __ATOMIC_RELAXED, __HIP_MEMORY_SCOPE_AGENT);
        }
        __syncthreads();   // drains vmcnt before flag
        if (t == 0) {
            __hip_atomic_fetch_add(&mycnt[s], 1, __ATOMIC_RELAXED, __HIP_MEMORY_SCOPE_AGENT);
            while (__hip_atomic_load(&mycnt[s], __ATOMIC_RELAXED, __HIP_MEMORY_SCOPE_AGENT) < 4)
                __builtin_amdgcn_s_sleep(1);
        }
        __syncthreads();
    }

    {
        #pragma unroll
        for (int i = 0; i < 4; ++i) {
            int j = t + 512 * i;
            int batch = j >> 7, within = j & 127;
            unsigned v = __hip_atomic_load(
                &hx[(size_t)(bg * DB + batch) * 128 + within],
                __ATOMIC_RELAXED, __HIP_MEMORY_SCOPE_AGENT);
            hlU[batch][within] = v;
        }
        __syncthreads();
        int batch = t >> 5, seg = t & 31;
        half8 hv = *reinterpret_cast<const half8*>(
            reinterpret_cast<const char*>(hlU) + batch * 528 + seg * 16);
        float sum = 0.f;
        #pragma unroll
        for (int j = 0; j < 8; ++j) sum += (float)hv[j] * owl[8 * seg + j];
        #pragma unroll
        for (int m = 1; m < 32; m <<= 1) sum += __shfl_xor(sum, m);
        if (q == 0 && seg == 0)
            out[(size_t)(bg * DB + batch) * T_DEC + (T_DEC - 1)] = sum + ob;
    }
}

extern "C" void kernel_launch(void* const* d_in, const int* in_sizes, int n_in,
                              void* d_out, int out_size, void* d_ws, size_t ws_size,
                              hipStream_t stream) {
    const float* source = (const float*)d_in[0];
    const float* eWih_f = (const float*)d_in[2];
    const float* eWhh_f = (const float*)d_in[3];
    const float* eb_f   = (const float*)d_in[4];
    const float* eWih_b = (const float*)d_in[5];
    const float* eWhh_b = (const float*)d_in[6];
    const float* eb_b   = (const float*)d_in[7];
    const float* dWih   = (const float*)d_in[8];
    const float* dWhh   = (const float*)d_in[9];
    const float* db     = (const float*)d_in[10];
    const float* oW     = (const float*)d_in[11];
    const float* obp    = (const float*)d_in[12];
    float* out = (float*)d_out;

    float*    h0  = (float*)d_ws;                             // 1 MB
    float*    c0  = h0 + (size_t)B_TOT * H_DEC;               // 1 MB
    unsigned* hx  = (unsigned*)(c0 + (size_t)B_TOT * H_DEC);  // 1 MB
    int*      cnt = (int*)(hx + (size_t)2 * B_TOT * 128);     // 64*104 ints

    zero_cnt<<<(64 * CNT_STRIDE + 255) / 256, 256, 0, stream>>>(cnt);
    encoder_swz<<<128 * 2, 512, 0, stream>>>(
        source, eWih_f, eWhh_f, eb_f, eWih_b, eWhh_b, eb_b, h0, c0);
    decoder_split<<<256, 512, 0, stream>>>(   // literal 256: 64 groups x 4 chunks
        dWih, db, oW, obp, h0, c0, dWhh, hx, cnt, out);
}